// Round 3
// baseline (373.741 us; speedup 1.0000x reference)
//
#include <hip/hip_runtime.h>
#include <math.h>

#define NENTITY   100000
#define NRELATION 500
#define HID       100
#define HOUSE_DIM 4
#define HOUSE_NUM 10
#define HOUSD_NUM 2
#define B_SZ      512
#define NEG       256
#define THRED     0.5f
#define GAMMA     12.0f

#define TPN       4            // threads per negative
#define HPT       (HID / TPN)  // hids per thread = 25
#define BLOCK     (NEG * TPN)  // 1024

__device__ __forceinline__ float dot4(const float4 a, const float4 b) {
    return a.x * b.x + a.y * b.y + a.z * b.z + a.w * b.w;
}

__device__ __forceinline__ float4 norm4(float4 v) {
    float n = fmaxf(sqrtf(dot4(v, v)), 1e-12f);
    const float inv = 1.0f / n;
    v.x *= inv; v.y *= inv; v.z *= inv; v.w *= inv;
    return v;
}

__device__ __forceinline__ float4 reflect4(float4 x, const float4 v, const float coef) {
    // x - coef * <v,x> * v
    const float s = coef * dot4(v, x);
    x.x -= s * v.x;
    x.y -= s * v.y;
    x.z -= s * v.z;
    x.w -= s * v.w;
    return x;
}

__global__ __launch_bounds__(BLOCK, 8) void house_score_kernel(
    const float* __restrict__ ent,      // [NENTITY, HID, 4]
    const float* __restrict__ rel,      // [NRELATION, HID, 40]
    const float* __restrict__ kdh,      // [NRELATION, 1, 2]
    const float* __restrict__ kdt,      // [NRELATION, 1, 2]
    const float* __restrict__ ksh,      // [NRELATION, HID, 2]
    const float* __restrict__ kst,      // [NRELATION, HID, 2]
    const int* __restrict__ head_idx,   // [B]
    const int* __restrict__ rel_idx,    // [B]
    const int* __restrict__ tail_idx,   // [B, NEG]
    float* __restrict__ out)            // [B, NEG]
{
    __shared__ float4 sHead[HID];  // transformed head, per hid
    __shared__ float4 sV0[HID];    // normalized house 0 (tail)
    __shared__ float4 sV1[HID];    // normalized house 1 (tail)
    __shared__ float2 sKt[HID];    // clamped tail coefs

    const int b = blockIdx.x;
    const int t = threadIdx.x;
    const int r = rel_idx[b];

    // ---- Prep phase: threads 0..99, one hid each; houses streamed to keep
    //      VGPR pressure under the 64-reg cap from __launch_bounds__(1024,8) ----
    if (t < HID) {
        const int h = t;
        const float4* rr = (const float4*)(rel + ((size_t)r * HID + h) * (HOUSE_NUM * HOUSE_DIM));

        const int he = head_idx[b];
        float4 hd = ((const float4*)ent)[(size_t)he * HID + h];

        const float kh0 = fminf(kdh[r * 2 + 0] * fabsf(ksh[((size_t)r * HID + h) * 2 + 0]), THRED);
        const float kh1 = fminf(kdh[r * 2 + 1] * fabsf(ksh[((size_t)r * HID + h) * 2 + 1]), THRED);

        // head reflections: house 9 (kh0), house 8 (kh1), houses 7..2 (coef 2)
        hd = reflect4(hd, norm4(rr[9]), kh0);
        hd = reflect4(hd, norm4(rr[8]), kh1);
        #pragma unroll
        for (int j = 7; j >= 2; --j) hd = reflect4(hd, norm4(rr[j]), 2.0f);

        const float kt0 = fminf(kdt[r * 2 + 0] * fabsf(kst[((size_t)r * HID + h) * 2 + 0]), THRED);
        const float kt1 = fminf(kdt[r * 2 + 1] * fabsf(kst[((size_t)r * HID + h) * 2 + 1]), THRED);

        sHead[h] = hd;
        sV0[h]   = norm4(rr[0]);
        sV1[h]   = norm4(rr[1]);
        sKt[h]   = make_float2(kt0, kt1);
    }
    __syncthreads();

    // ---- Main phase: TPN threads per negative, HPT hids each ----
    const int neg = t >> 2;        // t / TPN
    const int c   = t & (TPN - 1); // hid-chunk index
    const int e = tail_idx[(size_t)b * NEG + neg];
    const float4* trow = (const float4*)(ent + (size_t)e * HID * HOUSE_DIM);

    const int h0 = c * HPT;
    float acc = 0.0f;
    #pragma unroll 5
    for (int hh = 0; hh < HPT; ++hh) {
        const int h = h0 + hh;
        float4 tv = trow[h];

        const float2 kt = sKt[h];
        const float4 v0 = sV0[h];
        const float s0 = kt.x * dot4(v0, tv);
        tv.x -= s0 * v0.x; tv.y -= s0 * v0.y; tv.z -= s0 * v0.z; tv.w -= s0 * v0.w;

        const float4 v1 = sV1[h];
        const float s1 = kt.y * dot4(v1, tv);
        tv.x -= s1 * v1.x; tv.y -= s1 * v1.y; tv.z -= s1 * v1.z; tv.w -= s1 * v1.w;

        const float4 hd = sHead[h];
        const float dx = hd.x - tv.x;
        const float dy = hd.y - tv.y;
        const float dz = hd.z - tv.z;
        const float dw = hd.w - tv.w;
        acc += sqrtf(dx * dx + dy * dy + dz * dz + dw * dw);
    }

    // combine the 4 partial sums (partners are in-wave: t^1, t^2)
    acc += __shfl_xor(acc, 1);
    acc += __shfl_xor(acc, 2);
    if (c == 0) out[(size_t)b * NEG + neg] = GAMMA - acc;
}

extern "C" void kernel_launch(void* const* d_in, const int* in_sizes, int n_in,
                              void* d_out, int out_size, void* d_ws, size_t ws_size,
                              hipStream_t stream) {
    const float* ent = (const float*)d_in[0];
    const float* rel = (const float*)d_in[1];
    const float* kdh = (const float*)d_in[2];
    const float* kdt = (const float*)d_in[3];
    const float* ksh = (const float*)d_in[4];
    const float* kst = (const float*)d_in[5];
    const int* head_idx = (const int*)d_in[6];
    const int* rel_idx  = (const int*)d_in[7];
    const int* tail_idx = (const int*)d_in[8];
    float* out = (float*)d_out;

    house_score_kernel<<<B_SZ, BLOCK, 0, stream>>>(
        ent, rel, kdh, kdt, ksh, kst, head_idx, rel_idx, tail_idx, out);
}

// Round 4
// 243.222 us; speedup vs baseline: 1.5366x; 1.5366x over previous
//
#include <hip/hip_runtime.h>
#include <math.h>

#define NENTITY   100000
#define NRELATION 500
#define HID       100
#define HOUSE_DIM 4
#define HOUSE_NUM 10
#define B_SZ      512
#define NEG       256
#define THRED     0.5f
#define GAMMA     12.0f

#define SEGS           4                    // blocks per batch row
#define NEG_PER_BLOCK  (NEG / SEGS)         // 64
#define BLOCK          256                  // 4 waves
#define NEG_PER_WAVE   (NEG_PER_BLOCK / 4)  // 16

__device__ __forceinline__ float dot4(const float4 a, const float4 b) {
    return a.x * b.x + a.y * b.y + a.z * b.z + a.w * b.w;
}

__device__ __forceinline__ float4 norm4(float4 v) {
    const float n = fmaxf(sqrtf(dot4(v, v)), 1e-12f);
    const float inv = 1.0f / n;
    v.x *= inv; v.y *= inv; v.z *= inv; v.w *= inv;
    return v;
}

__device__ __forceinline__ float4 reflect4(float4 x, const float4 v, const float coef) {
    const float s = coef * dot4(v, x);
    x.x -= s * v.x; x.y -= s * v.y; x.z -= s * v.z; x.w -= s * v.w;
    return x;
}

// apply two tail reflections then return ||hd - tv||
__device__ __forceinline__ float hdist(float4 tv, const float4 v0, const float4 v1,
                                       const float2 kt, const float4 hd) {
    const float s0 = kt.x * dot4(v0, tv);
    tv.x -= s0 * v0.x; tv.y -= s0 * v0.y; tv.z -= s0 * v0.z; tv.w -= s0 * v0.w;
    const float s1 = kt.y * dot4(v1, tv);
    tv.x -= s1 * v1.x; tv.y -= s1 * v1.y; tv.z -= s1 * v1.z; tv.w -= s1 * v1.w;
    const float dx = hd.x - tv.x;
    const float dy = hd.y - tv.y;
    const float dz = hd.z - tv.z;
    const float dw = hd.w - tv.w;
    return sqrtf(dx * dx + dy * dy + dz * dz + dw * dw);
}

__global__ __launch_bounds__(BLOCK, 6) void house_score_kernel(
    const float* __restrict__ ent,      // [NENTITY, HID, 4]
    const float* __restrict__ rel,      // [NRELATION, HID, 40]
    const float* __restrict__ kdh,      // [NRELATION, 1, 2]
    const float* __restrict__ kdt,      // [NRELATION, 1, 2]
    const float* __restrict__ ksh,      // [NRELATION, HID, 2]
    const float* __restrict__ kst,      // [NRELATION, HID, 2]
    const int* __restrict__ head_idx,   // [B]
    const int* __restrict__ rel_idx,    // [B]
    const int* __restrict__ tail_idx,   // [B, NEG]
    float* __restrict__ out)            // [B, NEG]
{
    __shared__ float4 sHead[HID];
    __shared__ float4 sV0[HID];
    __shared__ float4 sV1[HID];
    __shared__ float2 sKt[HID];

    const int blk = blockIdx.x;
    const int b   = blk >> 2;          // SEGS = 4
    const int seg = blk & (SEGS - 1);
    const int tid = threadIdx.x;
    const int r   = rel_idx[b];

    // ---- Prep: threads 0..99, one hid each (streamed houses, low VGPR) ----
    if (tid < HID) {
        const int h = tid;
        const float4* rr = (const float4*)(rel + ((size_t)r * HID + h) * (HOUSE_NUM * HOUSE_DIM));

        const int he = head_idx[b];
        float4 hd = ((const float4*)ent)[(size_t)he * HID + h];

        const float kh0 = fminf(kdh[r * 2 + 0] * fabsf(ksh[((size_t)r * HID + h) * 2 + 0]), THRED);
        const float kh1 = fminf(kdh[r * 2 + 1] * fabsf(ksh[((size_t)r * HID + h) * 2 + 1]), THRED);

        hd = reflect4(hd, norm4(rr[9]), kh0);
        hd = reflect4(hd, norm4(rr[8]), kh1);
        #pragma unroll
        for (int j = 7; j >= 2; --j) hd = reflect4(hd, norm4(rr[j]), 2.0f);

        const float kt0 = fminf(kdt[r * 2 + 0] * fabsf(kst[((size_t)r * HID + h) * 2 + 0]), THRED);
        const float kt1 = fminf(kdt[r * 2 + 1] * fabsf(kst[((size_t)r * HID + h) * 2 + 1]), THRED);

        sHead[h] = hd;
        sV0[h]   = norm4(rr[0]);
        sV1[h]   = norm4(rr[1]);
        sKt[h]   = make_float2(kt0, kt1);
    }
    __syncthreads();

    // ---- Main: each wave processes one neg at a time; 64 lanes read ONE row
    //      cooperatively (full cache-line consumption per instruction). ----
    const int w = tid >> 6;   // wave in block
    const int l = tid & 63;   // lane

    // lane l owns hids {l, 64+l (l<36)} — hoist per-hid constants to registers
    const float4 hd1 = sHead[l];
    const float4 v01 = sV0[l];
    const float4 v11 = sV1[l];
    const float2 k1  = sKt[l];
    const int   l2   = (l < 36) ? (64 + l) : 99;  // clamped for safe address
    const float4 hd2 = sHead[l2];
    const float4 v02 = sV0[l2];
    const float4 v12 = sV1[l2];
    const float2 k2  = sKt[l2];
    const bool has2  = (l < 36);

    const int negbase = seg * NEG_PER_BLOCK + w * NEG_PER_WAVE;

    // preload this wave's 16 tail indices into lanes 0..15
    int my_e = 0;
    if (l < NEG_PER_WAVE) my_e = tail_idx[(size_t)b * NEG + negbase + l];

    const float4* entf4 = (const float4*)ent;

    #pragma unroll 4
    for (int i = 0; i < NEG_PER_WAVE; ++i) {
        const int e = __shfl(my_e, i);
        const float4* row = entf4 + (size_t)e * HID;

        const float4 t1 = row[l];                       // bytes 0..1023 of row
        float d2 = 0.0f;
        if (has2) {
            const float4 t2 = row[64 + l];              // bytes 1024..1599
            d2 = hdist(t2, v02, v12, k2, hd2);
        }
        float s = hdist(t1, v01, v11, k1, hd1) + d2;

        // wave-wide sum over the 100 hids
        #pragma unroll
        for (int m = 1; m < 64; m <<= 1) s += __shfl_xor(s, m);

        if (l == 0) out[(size_t)b * NEG + negbase + i] = GAMMA - s;
    }
}

extern "C" void kernel_launch(void* const* d_in, const int* in_sizes, int n_in,
                              void* d_out, int out_size, void* d_ws, size_t ws_size,
                              hipStream_t stream) {
    const float* ent = (const float*)d_in[0];
    const float* rel = (const float*)d_in[1];
    const float* kdh = (const float*)d_in[2];
    const float* kdt = (const float*)d_in[3];
    const float* ksh = (const float*)d_in[4];
    const float* kst = (const float*)d_in[5];
    const int* head_idx = (const int*)d_in[6];
    const int* rel_idx  = (const int*)d_in[7];
    const int* tail_idx = (const int*)d_in[8];
    float* out = (float*)d_out;

    house_score_kernel<<<B_SZ * SEGS, BLOCK, 0, stream>>>(
        ent, rel, kdh, kdt, ksh, kst, head_idx, rel_idx, tail_idx, out);
}